// Round 2
// baseline (171.289 us; speedup 1.0000x reference)
//
#include <hip/hip_runtime.h>
#include <math.h>

// SIREN forward: coords [N,3] -> first(3->5,sin) -> 256 x hidden(5->5,sin) -> final(5->1)
// Output layout: d_out[0..N) = net output, d_out[N..4N) = coords passthrough.
//
// Round 2:
//  - UNIFORM control flow (index clamp, no early return) so the uniform-address
//    weight loads scalarize to s_load_* (K$), freeing the VALU of address junk.
//    Round-1 counters implied ~194 VALU cyc/layer vs ~110 intended -> divergent-CF
//    guard was blocking scalarization.
//  - Prep kernel pre-scales W,b by 30/(2pi) into d_ws (packed [256][32] floats,
//    128B-aligned per layer) -> inner loop loses the per-neuron mul AND the
//    fract (|z| <= ~3 revolutions, v_sin_f32 domain is [-256,256]).
//  - Inner loop target: 25 v_fma + 5 bias mov + 5 v_sin per layer.

#define SIREN_HID 5
#define SIREN_NLAYERS 256
// 30 / (2*pi)
#define SIREN_REV 4.774648292756860f

// ---------------- prep: scale weights into revolution units ----------------
// d_ws layout (floats):
//   [0 .. 8192)        hidden layers: layer l at l*32: w[0..24], b[25..29], pad[30..31]
//   [8192 .. 8207)     first layer W (5x3, row-major), scaled
//   [8207 .. 8212)     first layer b, scaled
__global__ __launch_bounds__(256)
void siren_prep(const float* __restrict__ Wf, const float* __restrict__ bf,
                const float* __restrict__ Wh, const float* __restrict__ bh,
                float* __restrict__ ws)
{
    int t = blockIdx.x * blockDim.x + threadIdx.x;
    const int total = SIREN_NLAYERS * 32;
    for (int idx = t; idx < total; idx += gridDim.x * blockDim.x) {
        int l = idx >> 5;
        int k = idx & 31;
        float v = 0.0f;
        if (k < 25)      v = Wh[l * 25 + k] * SIREN_REV;
        else if (k < 30) v = bh[l * 5 + (k - 25)] * SIREN_REV;
        ws[idx] = v;
    }
    if (t < 15) ws[total + t]      = Wf[t] * SIREN_REV;
    if (t < 5)  ws[total + 15 + t] = bf[t] * SIREN_REV;
}

// ---------------- main ----------------
__global__ __launch_bounds__(256)
void siren_fwd2(const float* __restrict__ coords,
                const float* __restrict__ lw,    // [256][32] scaled hidden w/b
                const float* __restrict__ fw,    // [20] scaled first-layer w(15)+b(5)
                const float* __restrict__ Wfin,  // [1][5] (unscaled)
                const float* __restrict__ bfin,  // [1]
                float* __restrict__ out, int N)
{
    int i = blockIdx.x * blockDim.x + threadIdx.x;
    i = (i < N) ? i : (N - 1);   // clamp: keeps control flow UNIFORM (no divergent return)

    float c0 = coords[3 * i + 0];
    float c1 = coords[3 * i + 1];
    float c2 = coords[3 * i + 2];

    // first layer (already in revolution units): h_j = sin_rev(c . w[j,:] + b[j])
    float h0, h1, h2, h3, h4;
    {
        float t0 = fmaf(c2, fw[ 2], fmaf(c1, fw[ 1], fmaf(c0, fw[ 0], fw[15])));
        float t1 = fmaf(c2, fw[ 5], fmaf(c1, fw[ 4], fmaf(c0, fw[ 3], fw[16])));
        float t2 = fmaf(c2, fw[ 8], fmaf(c1, fw[ 7], fmaf(c0, fw[ 6], fw[17])));
        float t3 = fmaf(c2, fw[11], fmaf(c1, fw[10], fmaf(c0, fw[ 9], fw[18])));
        float t4 = fmaf(c2, fw[14], fmaf(c1, fw[13], fmaf(c0, fw[12], fw[19])));
        // |t| <= ~7.6 revolutions: inside v_sin_f32 domain, no fract needed
        h0 = __builtin_amdgcn_sinf(t0);
        h1 = __builtin_amdgcn_sinf(t1);
        h2 = __builtin_amdgcn_sinf(t2);
        h3 = __builtin_amdgcn_sinf(t3);
        h4 = __builtin_amdgcn_sinf(t4);
    }

    // 256 hidden layers, weights in revolution units: h' = sin_rev(h . w^T + b)
#pragma unroll 2
    for (int l = 0; l < SIREN_NLAYERS; ++l) {
        const float* w = lw + l * 32;
        float t0 = fmaf(h4, w[ 4], fmaf(h3, w[ 3], fmaf(h2, w[ 2], fmaf(h1, w[ 1], fmaf(h0, w[ 0], w[25])))));
        float t1 = fmaf(h4, w[ 9], fmaf(h3, w[ 8], fmaf(h2, w[ 7], fmaf(h1, w[ 6], fmaf(h0, w[ 5], w[26])))));
        float t2 = fmaf(h4, w[14], fmaf(h3, w[13], fmaf(h2, w[12], fmaf(h1, w[11], fmaf(h0, w[10], w[27])))));
        float t3 = fmaf(h4, w[19], fmaf(h3, w[18], fmaf(h2, w[17], fmaf(h1, w[16], fmaf(h0, w[15], w[28])))));
        float t4 = fmaf(h4, w[24], fmaf(h3, w[23], fmaf(h2, w[22], fmaf(h1, w[21], fmaf(h0, w[20], w[29])))));
        // |t| <= ~3.0 revolutions
        h0 = __builtin_amdgcn_sinf(t0);
        h1 = __builtin_amdgcn_sinf(t1);
        h2 = __builtin_amdgcn_sinf(t2);
        h3 = __builtin_amdgcn_sinf(t3);
        h4 = __builtin_amdgcn_sinf(t4);
    }

    // final linear (plain units, no sine)
    float o = fmaf(h4, Wfin[4], fmaf(h3, Wfin[3], fmaf(h2, Wfin[2], fmaf(h1, Wfin[1], fmaf(h0, Wfin[0], bfin[0])))));
    out[i] = o;

    float* oc = out + N;
    oc[3 * i + 0] = c0;
    oc[3 * i + 1] = c1;
    oc[3 * i + 2] = c2;
}

// ---------------- fallback (round-1 style, used only if ws too small) -------
__global__ __launch_bounds__(256)
void siren_fwd_fallback(const float* __restrict__ coords,
                        const float* __restrict__ Wf, const float* __restrict__ bf,
                        const float* __restrict__ Wh, const float* __restrict__ bh,
                        const float* __restrict__ Wfin, const float* __restrict__ bfin,
                        float* __restrict__ out, int N)
{
    int i = blockIdx.x * blockDim.x + threadIdx.x;
    i = (i < N) ? i : (N - 1);
    float c0 = coords[3 * i + 0], c1 = coords[3 * i + 1], c2 = coords[3 * i + 2];
    float h0, h1, h2, h3, h4;
    {
        float t0 = fmaf(c2, Wf[2],  fmaf(c1, Wf[1],  fmaf(c0, Wf[0],  bf[0]))) * SIREN_REV;
        float t1 = fmaf(c2, Wf[5],  fmaf(c1, Wf[4],  fmaf(c0, Wf[3],  bf[1]))) * SIREN_REV;
        float t2 = fmaf(c2, Wf[8],  fmaf(c1, Wf[7],  fmaf(c0, Wf[6],  bf[2]))) * SIREN_REV;
        float t3 = fmaf(c2, Wf[11], fmaf(c1, Wf[10], fmaf(c0, Wf[9],  bf[3]))) * SIREN_REV;
        float t4 = fmaf(c2, Wf[14], fmaf(c1, Wf[13], fmaf(c0, Wf[12], bf[4]))) * SIREN_REV;
        h0 = __builtin_amdgcn_sinf(t0); h1 = __builtin_amdgcn_sinf(t1);
        h2 = __builtin_amdgcn_sinf(t2); h3 = __builtin_amdgcn_sinf(t3);
        h4 = __builtin_amdgcn_sinf(t4);
    }
#pragma unroll 2
    for (int l = 0; l < SIREN_NLAYERS; ++l) {
        const float* w = Wh + l * 25;
        const float* b = bh + l * 5;
        float t0 = fmaf(h4, w[ 4], fmaf(h3, w[ 3], fmaf(h2, w[ 2], fmaf(h1, w[ 1], fmaf(h0, w[ 0], b[0]))))) * SIREN_REV;
        float t1 = fmaf(h4, w[ 9], fmaf(h3, w[ 8], fmaf(h2, w[ 7], fmaf(h1, w[ 6], fmaf(h0, w[ 5], b[1]))))) * SIREN_REV;
        float t2 = fmaf(h4, w[14], fmaf(h3, w[13], fmaf(h2, w[12], fmaf(h1, w[11], fmaf(h0, w[10], b[2]))))) * SIREN_REV;
        float t3 = fmaf(h4, w[19], fmaf(h3, w[18], fmaf(h2, w[17], fmaf(h1, w[16], fmaf(h0, w[15], b[3]))))) * SIREN_REV;
        float t4 = fmaf(h4, w[24], fmaf(h3, w[23], fmaf(h2, w[22], fmaf(h1, w[21], fmaf(h0, w[20], b[4]))))) * SIREN_REV;
        h0 = __builtin_amdgcn_sinf(t0); h1 = __builtin_amdgcn_sinf(t1);
        h2 = __builtin_amdgcn_sinf(t2); h3 = __builtin_amdgcn_sinf(t3);
        h4 = __builtin_amdgcn_sinf(t4);
    }
    float o = fmaf(h4, Wfin[4], fmaf(h3, Wfin[3], fmaf(h2, Wfin[2], fmaf(h1, Wfin[1], fmaf(h0, Wfin[0], bfin[0])))));
    out[i] = o;
    float* oc = out + N;
    oc[3 * i + 0] = c0; oc[3 * i + 1] = c1; oc[3 * i + 2] = c2;
}

extern "C" void kernel_launch(void* const* d_in, const int* in_sizes, int n_in,
                              void* d_out, int out_size, void* d_ws, size_t ws_size,
                              hipStream_t stream) {
    const float* coords = (const float*)d_in[0];
    const float* Wf     = (const float*)d_in[1];
    const float* bf     = (const float*)d_in[2];
    const float* Wh     = (const float*)d_in[3];
    const float* bh     = (const float*)d_in[4];
    const float* Wfin   = (const float*)d_in[5];
    const float* bfin   = (const float*)d_in[6];

    int N = in_sizes[0] / 3;
    float* out = (float*)d_out;

    const size_t ws_need = (size_t)(SIREN_NLAYERS * 32 + 20) * sizeof(float);

    dim3 block(256);
    dim3 grid((N + 255) / 256);

    if (ws_size >= ws_need) {
        float* ws = (float*)d_ws;
        hipLaunchKernelGGL(siren_prep, dim3(32), dim3(256), 0, stream, Wf, bf, Wh, bh, ws);
        hipLaunchKernelGGL(siren_fwd2, grid, block, 0, stream,
                           coords, ws, ws + SIREN_NLAYERS * 32, Wfin, bfin, out, N);
    } else {
        hipLaunchKernelGGL(siren_fwd_fallback, grid, block, 0, stream,
                           coords, Wf, bf, Wh, bh, Wfin, bfin, out, N);
    }
}

// Round 3
// 163.059 us; speedup vs baseline: 1.0505x; 1.0505x over previous
//
#include <hip/hip_runtime.h>
#include <math.h>

// SIREN forward: coords [N,3] -> first(3->5,sin) -> 256 x hidden(5->5,sin) -> final(5->1)
// Output layout: d_out[0..N) = net output, d_out[N..4N) = coords passthrough.
//
// Round 3:
//  - 2 points per thread. Round-2 counters: VALUBusy 75%, sin=16cyc model fits ->
//    ~25% idle from redundant per-wave s_load streams + thin ILP (5 chains).
//    P=2 halves waves (halves scalar-fetch traffic), doubles independent
//    fma/sin chains per wave, amortizes bias v_movs across points.
//  - Weights pre-scaled by 30/(2pi) into d_ws ([256][32] floats): sin_rev
//    without fract (|args| <= ~3 revolutions, v_sin_f32 domain +-256).
//  - Uniform control flow (clamp, no early return) keeps weight loads scalar.

#define SIREN_HID 5
#define SIREN_NLAYERS 256
// 30 / (2*pi)
#define SIREN_REV 4.774648292756860f

// ---------------- prep: scale weights into revolution units ----------------
// d_ws layout (floats):
//   [0 .. 8192)        hidden layers: layer l at l*32: w[0..24], b[25..29], pad
//   [8192 .. 8207)     first layer W (5x3, row-major), scaled
//   [8207 .. 8212)     first layer b, scaled
__global__ __launch_bounds__(256)
void siren_prep(const float* __restrict__ Wf, const float* __restrict__ bf,
                const float* __restrict__ Wh, const float* __restrict__ bh,
                float* __restrict__ ws)
{
    int t = blockIdx.x * blockDim.x + threadIdx.x;
    const int total = SIREN_NLAYERS * 32;
    for (int idx = t; idx < total; idx += gridDim.x * blockDim.x) {
        int l = idx >> 5;
        int k = idx & 31;
        float v = 0.0f;
        if (k < 25)      v = Wh[l * 25 + k] * SIREN_REV;
        else if (k < 30) v = bh[l * 5 + (k - 25)] * SIREN_REV;
        ws[idx] = v;
    }
    if (t < 15) ws[total + t]      = Wf[t] * SIREN_REV;
    if (t < 5)  ws[total + 15 + t] = bf[t] * SIREN_REV;
}

// ---------------- main: 2 points per thread ----------------
__global__ __launch_bounds__(256)
void siren_fwd3(const float* __restrict__ coords,
                const float* __restrict__ lw,    // [256][32] scaled hidden w/b
                const float* __restrict__ fw,    // [20] scaled first w(15)+b(5)
                const float* __restrict__ Wfin,  // [1][5] (unscaled)
                const float* __restrict__ bfin,  // [1]
                float* __restrict__ out, int N)
{
    int i = blockIdx.x * blockDim.x + threadIdx.x;
    const int M = N >> 1;                 // pairs
    i = (i < M) ? i : (M - 1);            // uniform clamp, no divergent return

    // two adjacent points: 24B contiguous load
    const float* cp = coords + 6 * i;
    float a0 = cp[0], a1 = cp[1], a2 = cp[2];
    float b0 = cp[3], b1 = cp[4], b2 = cp[5];

    // first layer (revolution units): h_j = sin_rev(c . w[j,:] + b[j])
    float ha0, ha1, ha2, ha3, ha4;
    float hb0, hb1, hb2, hb3, hb4;
    {
        float s0 = fw[ 0], s1 = fw[ 1], s2 = fw[ 2], t0 = fw[15];
        float s3 = fw[ 3], s4 = fw[ 4], s5 = fw[ 5], t1 = fw[16];
        float s6 = fw[ 6], s7 = fw[ 7], s8 = fw[ 8], t2 = fw[17];
        float s9 = fw[ 9], sA = fw[10], sB = fw[11], t3 = fw[18];
        float sC = fw[12], sD = fw[13], sE = fw[14], t4 = fw[19];
        float za0 = fmaf(a2, s2, fmaf(a1, s1, fmaf(a0, s0, t0)));
        float za1 = fmaf(a2, s5, fmaf(a1, s4, fmaf(a0, s3, t1)));
        float za2 = fmaf(a2, s8, fmaf(a1, s7, fmaf(a0, s6, t2)));
        float za3 = fmaf(a2, sB, fmaf(a1, sA, fmaf(a0, s9, t3)));
        float za4 = fmaf(a2, sE, fmaf(a1, sD, fmaf(a0, sC, t4)));
        float zb0 = fmaf(b2, s2, fmaf(b1, s1, fmaf(b0, s0, t0)));
        float zb1 = fmaf(b2, s5, fmaf(b1, s4, fmaf(b0, s3, t1)));
        float zb2 = fmaf(b2, s8, fmaf(b1, s7, fmaf(b0, s6, t2)));
        float zb3 = fmaf(b2, sB, fmaf(b1, sA, fmaf(b0, s9, t3)));
        float zb4 = fmaf(b2, sE, fmaf(b1, sD, fmaf(b0, sC, t4)));
        ha0 = __builtin_amdgcn_sinf(za0); hb0 = __builtin_amdgcn_sinf(zb0);
        ha1 = __builtin_amdgcn_sinf(za1); hb1 = __builtin_amdgcn_sinf(zb1);
        ha2 = __builtin_amdgcn_sinf(za2); hb2 = __builtin_amdgcn_sinf(zb2);
        ha3 = __builtin_amdgcn_sinf(za3); hb3 = __builtin_amdgcn_sinf(zb3);
        ha4 = __builtin_amdgcn_sinf(za4); hb4 = __builtin_amdgcn_sinf(zb4);
    }

    // 256 hidden layers (revolution units)
#pragma unroll 2
    for (int l = 0; l < SIREN_NLAYERS; ++l) {
        const float* w = lw + l * 32;
        // biases first: one v_mov each, shared by both points' chains
        float p0 = w[25], p1 = w[26], p2 = w[27], p3 = w[28], p4 = w[29];
        float za0 = fmaf(ha4, w[ 4], fmaf(ha3, w[ 3], fmaf(ha2, w[ 2], fmaf(ha1, w[ 1], fmaf(ha0, w[ 0], p0)))));
        float zb0 = fmaf(hb4, w[ 4], fmaf(hb3, w[ 3], fmaf(hb2, w[ 2], fmaf(hb1, w[ 1], fmaf(hb0, w[ 0], p0)))));
        float za1 = fmaf(ha4, w[ 9], fmaf(ha3, w[ 8], fmaf(ha2, w[ 7], fmaf(ha1, w[ 6], fmaf(ha0, w[ 5], p1)))));
        float zb1 = fmaf(hb4, w[ 9], fmaf(hb3, w[ 8], fmaf(hb2, w[ 7], fmaf(hb1, w[ 6], fmaf(hb0, w[ 5], p1)))));
        float za2 = fmaf(ha4, w[14], fmaf(ha3, w[13], fmaf(ha2, w[12], fmaf(ha1, w[11], fmaf(ha0, w[10], p2)))));
        float zb2 = fmaf(hb4, w[14], fmaf(hb3, w[13], fmaf(hb2, w[12], fmaf(hb1, w[11], fmaf(hb0, w[10], p2)))));
        float za3 = fmaf(ha4, w[19], fmaf(ha3, w[18], fmaf(ha2, w[17], fmaf(ha1, w[16], fmaf(ha0, w[15], p3)))));
        float zb3 = fmaf(hb4, w[19], fmaf(hb3, w[18], fmaf(hb2, w[17], fmaf(hb1, w[16], fmaf(hb0, w[15], p3)))));
        float za4 = fmaf(ha4, w[24], fmaf(ha3, w[23], fmaf(ha2, w[22], fmaf(ha1, w[21], fmaf(ha0, w[20], p4)))));
        float zb4 = fmaf(hb4, w[24], fmaf(hb3, w[23], fmaf(hb2, w[22], fmaf(hb1, w[21], fmaf(hb0, w[20], p4)))));
        ha0 = __builtin_amdgcn_sinf(za0); hb0 = __builtin_amdgcn_sinf(zb0);
        ha1 = __builtin_amdgcn_sinf(za1); hb1 = __builtin_amdgcn_sinf(zb1);
        ha2 = __builtin_amdgcn_sinf(za2); hb2 = __builtin_amdgcn_sinf(zb2);
        ha3 = __builtin_amdgcn_sinf(za3); hb3 = __builtin_amdgcn_sinf(zb3);
        ha4 = __builtin_amdgcn_sinf(za4); hb4 = __builtin_amdgcn_sinf(zb4);
    }

    // final linear (plain units, no sine)
    float w0 = Wfin[0], w1 = Wfin[1], w2 = Wfin[2], w3 = Wfin[3], w4 = Wfin[4];
    float bb = bfin[0];
    float oa = fmaf(ha4, w4, fmaf(ha3, w3, fmaf(ha2, w2, fmaf(ha1, w1, fmaf(ha0, w0, bb)))));
    float ob = fmaf(hb4, w4, fmaf(hb3, w3, fmaf(hb2, w2, fmaf(hb1, w1, fmaf(hb0, w0, bb)))));

    out[2 * i + 0] = oa;
    out[2 * i + 1] = ob;

    float* oc = out + N + 6 * i;
    oc[0] = a0; oc[1] = a1; oc[2] = a2;
    oc[3] = b0; oc[4] = b1; oc[5] = b2;
}

extern "C" void kernel_launch(void* const* d_in, const int* in_sizes, int n_in,
                              void* d_out, int out_size, void* d_ws, size_t ws_size,
                              hipStream_t stream) {
    const float* coords = (const float*)d_in[0];
    const float* Wf     = (const float*)d_in[1];
    const float* bf     = (const float*)d_in[2];
    const float* Wh     = (const float*)d_in[3];
    const float* bh     = (const float*)d_in[4];
    const float* Wfin   = (const float*)d_in[5];
    const float* bfin   = (const float*)d_in[6];

    int N = in_sizes[0] / 3;
    float* out = (float*)d_out;
    float* ws = (float*)d_ws;

    hipLaunchKernelGGL(siren_prep, dim3(32), dim3(256), 0, stream, Wf, bf, Wh, bh, ws);

    int M = N / 2;                       // pairs; N = 524288 -> 262144
    dim3 block(256);
    dim3 grid((M + 255) / 256);
    hipLaunchKernelGGL(siren_fwd3, grid, block, 0, stream,
                       coords, ws, ws + SIREN_NLAYERS * 32, Wfin, bfin, out, N);
}

// Round 4
// 152.255 us; speedup vs baseline: 1.1250x; 1.0710x over previous
//
#include <hip/hip_runtime.h>
#include <math.h>

// SIREN forward: coords [N,3] -> first(3->5,sin) -> 256 x hidden(5->5,sin) -> final(5->1)
// Output layout: d_out[0..N) = net output, d_out[N..4N) = coords passthrough.
//
// Round 4:
//  - 4 points per thread (20 independent fma->sin chains per wave). Rounds 2/3
//    showed identical busy-cycles/point and ~22% VALU idle regardless of wave
//    count -> idle is dependency bubbles around the quarter-rate sin unit at
//    layer boundaries, not occupancy. More ILP per wave feeds both the trans
//    unit and the fma issue simultaneously.
//  - Weights pre-scaled by 30/(2pi) in d_ws ([256][32] f32, 128B/layer):
//    sin_rev without fract (|z| <= ~3 rev, v_sin_f32 domain +-256).
//  - Uniform control flow; weight reads stay scalar (s_load, K$).
//  - All arrays statically indexed after #pragma unroll (no scratch).

#define SIREN_HID 5
#define SIREN_NLAYERS 256
// 30 / (2*pi)
#define SIREN_REV 4.774648292756860f
#define PTS 4

// ---------------- prep: scale weights into revolution units ----------------
// d_ws layout (floats):
//   [0 .. 8192)        hidden layers: layer l at l*32: w[0..24], b[25..29], pad
//   [8192 .. 8207)     first layer W (5x3, row-major), scaled
//   [8207 .. 8212)     first layer b, scaled
__global__ __launch_bounds__(256)
void siren_prep(const float* __restrict__ Wf, const float* __restrict__ bf,
                const float* __restrict__ Wh, const float* __restrict__ bh,
                float* __restrict__ ws)
{
    int t = blockIdx.x * blockDim.x + threadIdx.x;
    const int total = SIREN_NLAYERS * 32;
    for (int idx = t; idx < total; idx += gridDim.x * blockDim.x) {
        int l = idx >> 5;
        int k = idx & 31;
        float v = 0.0f;
        if (k < 25)      v = Wh[l * 25 + k] * SIREN_REV;
        else if (k < 30) v = bh[l * 5 + (k - 25)] * SIREN_REV;
        ws[idx] = v;
    }
    if (t < 15) ws[total + t]      = Wf[t] * SIREN_REV;
    if (t < 5)  ws[total + 15 + t] = bf[t] * SIREN_REV;
}

// ---------------- main: 4 points per thread ----------------
__global__ __launch_bounds__(256)
void siren_fwd4(const float* __restrict__ coords,
                const float* __restrict__ lw,    // [256][32] scaled hidden w/b
                const float* __restrict__ fw,    // [20] scaled first w(15)+b(5)
                const float* __restrict__ Wfin,  // [1][5] (unscaled)
                const float* __restrict__ bfin,  // [1]
                float* __restrict__ out, int N)
{
    int i = blockIdx.x * blockDim.x + threadIdx.x;
    const int M = N / PTS;                // groups of 4 points
    i = (i < M) ? i : (M - 1);            // uniform clamp, no divergent return

    // 4 adjacent points: 48B contiguous load as 3x float4
    const float4* cp4 = (const float4*)(coords + 3 * PTS * i);
    float4 q0 = cp4[0];   // a0 a1 a2 b0
    float4 q1 = cp4[1];   // b1 b2 c0 c1
    float4 q2 = cp4[2];   // c2 d0 d1 d2
    float c[PTS][3] = {
        { q0.x, q0.y, q0.z },
        { q0.w, q1.x, q1.y },
        { q1.z, q1.w, q2.x },
        { q2.y, q2.z, q2.w },
    };

    float h[PTS][SIREN_HID];

    // first layer (revolution units): h_j = sin_rev(c . w[j,:] + b[j])
    {
#pragma unroll
        for (int p = 0; p < PTS; ++p) {
#pragma unroll
            for (int j = 0; j < SIREN_HID; ++j) {
                float z = fmaf(c[p][2], fw[3 * j + 2],
                          fmaf(c[p][1], fw[3 * j + 1],
                          fmaf(c[p][0], fw[3 * j + 0], fw[15 + j])));
                h[p][j] = __builtin_amdgcn_sinf(z);
            }
        }
    }

    // 256 hidden layers (revolution units)
#pragma unroll 2
    for (int l = 0; l < SIREN_NLAYERS; ++l) {
        const float* w = lw + l * 32;
        // biases: one v_mov each, shared by all 4 points' chains
        float b0 = w[25], b1 = w[26], b2 = w[27], b3 = w[28], b4 = w[29];
        float z[PTS][SIREN_HID];
#pragma unroll
        for (int p = 0; p < PTS; ++p) {
            z[p][0] = fmaf(h[p][4], w[ 4], fmaf(h[p][3], w[ 3], fmaf(h[p][2], w[ 2], fmaf(h[p][1], w[ 1], fmaf(h[p][0], w[ 0], b0)))));
            z[p][1] = fmaf(h[p][4], w[ 9], fmaf(h[p][3], w[ 8], fmaf(h[p][2], w[ 7], fmaf(h[p][1], w[ 6], fmaf(h[p][0], w[ 5], b1)))));
            z[p][2] = fmaf(h[p][4], w[14], fmaf(h[p][3], w[13], fmaf(h[p][2], w[12], fmaf(h[p][1], w[11], fmaf(h[p][0], w[10], b2)))));
            z[p][3] = fmaf(h[p][4], w[19], fmaf(h[p][3], w[18], fmaf(h[p][2], w[17], fmaf(h[p][1], w[16], fmaf(h[p][0], w[15], b3)))));
            z[p][4] = fmaf(h[p][4], w[24], fmaf(h[p][3], w[23], fmaf(h[p][2], w[22], fmaf(h[p][1], w[21], fmaf(h[p][0], w[20], b4)))));
        }
#pragma unroll
        for (int p = 0; p < PTS; ++p) {
#pragma unroll
            for (int j = 0; j < SIREN_HID; ++j)
                h[p][j] = __builtin_amdgcn_sinf(z[p][j]);
        }
    }

    // final linear (plain units, no sine)
    float w0 = Wfin[0], w1 = Wfin[1], w2 = Wfin[2], w3 = Wfin[3], w4 = Wfin[4];
    float bb = bfin[0];
    float o[PTS];
#pragma unroll
    for (int p = 0; p < PTS; ++p)
        o[p] = fmaf(h[p][4], w4, fmaf(h[p][3], w3, fmaf(h[p][2], w2, fmaf(h[p][1], w1, fmaf(h[p][0], w0, bb)))));

    // contiguous 16B store of the 4 outputs
    float4* op4 = (float4*)(out + PTS * i);
    *op4 = make_float4(o[0], o[1], o[2], o[3]);

    // coords passthrough (second tuple element), 48B contiguous
    float4* oc4 = (float4*)(out + N + 3 * PTS * i);
    oc4[0] = q0; oc4[1] = q1; oc4[2] = q2;
}

extern "C" void kernel_launch(void* const* d_in, const int* in_sizes, int n_in,
                              void* d_out, int out_size, void* d_ws, size_t ws_size,
                              hipStream_t stream) {
    const float* coords = (const float*)d_in[0];
    const float* Wf     = (const float*)d_in[1];
    const float* bf     = (const float*)d_in[2];
    const float* Wh     = (const float*)d_in[3];
    const float* bh     = (const float*)d_in[4];
    const float* Wfin   = (const float*)d_in[5];
    const float* bfin   = (const float*)d_in[6];

    int N = in_sizes[0] / 3;
    float* out = (float*)d_out;
    float* ws = (float*)d_ws;

    hipLaunchKernelGGL(siren_prep, dim3(32), dim3(256), 0, stream, Wf, bf, Wh, bh, ws);

    int M = N / PTS;                     // 4 points per thread; N=524288 -> 131072
    dim3 block(256);
    dim3 grid((M + 255) / 256);
    hipLaunchKernelGGL(siren_fwd4, grid, block, 0, stream,
                       coords, ws, ws + SIREN_NLAYERS * 32, Wfin, bfin, out, N);
}